// Round 3
// baseline (2495.162 us; speedup 1.0000x reference)
//
#include <hip/hip_runtime.h>
#include <hip/hip_fp16.h>

// Elman RNN via MFMA:
//   prep:   pack W1x/W1h into 16x16x32 B-fragment tables; W23=W2@W3, b23=b2@W3+b3
//   phase1: premb[v][j] = f16( emb[v]@W1x + b1 )  -- MFMA GEMM, 500 blocks x 64 rows
//   phase2: 8 blocks x 16 batches; per step H_new = sigmoid(premb[tok] + H@W1h) via MFMA,
//           W1h frags register-resident, H ping-pong in LDS, 1 barrier/step
//   phase3: out = h @ W23 + b23 (one wave per (b,t) row)

typedef _Float16 f16x8 __attribute__((ext_vector_type(8)));
typedef _Float16 f16x4 __attribute__((ext_vector_type(4)));
typedef float f32x4 __attribute__((ext_vector_type(4)));

#define NVOCAB 32000
#define NB 128
#define NT 512

// workspace byte offsets
#define OFF_PREMB 0ull                 // f16 [32000][300]            = 19,200,000
#define OFF_HALL  19200000ull          // u32 [65536][152]            = 39,845,888
#define OFF_PW2X  59045888ull          // f16 frag table [10][20][64][8] = 204,800
#define OFF_PW2H  59250688ull          // f16 frag table                 = 204,800
#define OFF_W23   59455488ull          // f32 [300][2]                =      2,400
#define OFF_B23   59457888ull          // f32 [2]

#define HSTRIDE 328                    // halves per H-tile row (656B, 16B-aligned, conflict-free)

__device__ __forceinline__ f32x4 mfma16(f16x8 a, f16x8 b, f32x4 c) {
  return __builtin_amdgcn_mfma_f32_16x16x32_f16(a, b, c, 0, 0, 0);
}

// ---------------- prep: fragment tables + W23/b23 ----------------
// B-frag convention (matches A-frag load in phase1/2): element e of lane l holds
// W[k = 32*kt + 8*(l/16) + e][j = 16*jt + (l%16)], zero-padded outside 300x300.
__global__ __launch_bounds__(256) void rnn_prep(const float* __restrict__ W1,
                                                const float* __restrict__ W2,
                                                const float* __restrict__ b2,
                                                const float* __restrict__ W3,
                                                const float* __restrict__ b3,
                                                unsigned char* __restrict__ ws) {
  unsigned int tid = blockIdx.x * 256 + threadIdx.x;
  if (tid < 204800u) {
    int part = tid / 102400;          // 0 = W1x (k rows 0..299), 1 = W1h (rows 300..599)
    int f = tid % 102400;
    int e = f & 7, l = (f >> 3) & 63, jt = (f >> 9) % 20, kt = f / 10240;
    int g = l >> 4, m = l & 15;
    int k = 32 * kt + 8 * g + e;
    int j = 16 * jt + m;
    _Float16 val = (_Float16)0.f;
    if (k < 300 && j < 300) val = (_Float16)W1[(size_t)(part * 300 + k) * 300 + j];
    ((_Float16*)(ws + (part ? OFF_PW2H : OFF_PW2X)))[f] = val;
  } else if (tid < 205100u) {
    int j = tid - 204800;
    float s0 = 0.f, s1 = 0.f;
    for (int k = 0; k < 300; ++k) {
      float w = W2[j * 300 + k];
      s0 += w * W3[k * 2 + 0];
      s1 += w * W3[k * 2 + 1];
    }
    float* w23 = (float*)(ws + OFF_W23);
    w23[j * 2 + 0] = s0;
    w23[j * 2 + 1] = s1;
  } else if (tid == 205100u) {
    float s0 = b3[0], s1 = b3[1];
    for (int k = 0; k < 300; ++k) {
      s0 += b2[k] * W3[k * 2 + 0];
      s1 += b2[k] * W3[k * 2 + 1];
    }
    float* b23 = (float*)(ws + OFF_B23);
    b23[0] = s0; b23[1] = s1;
  }
}

// ---------------- phase1: premb = f16(emb @ W1x + b1) ----------------
__global__ __launch_bounds__(256, 1) void rnn_phase1(const float* __restrict__ emb,
                                                     const float* __restrict__ b1,
                                                     unsigned char* __restrict__ ws) {
  __shared__ _Float16 At[16 * HSTRIDE];
  const int tid = threadIdx.x;
  const int w = tid >> 6, l = tid & 63, g = l >> 4, m = l & 15;
  const f16x8* pwx2 = (const f16x8*)(ws + OFF_PW2X);
  _Float16* premb = (_Float16*)(ws + OFF_PREMB);

  f16x8 bw[5][10];
#pragma unroll
  for (int n = 0; n < 5; ++n)
#pragma unroll
    for (int kt = 0; kt < 10; ++kt)
      bw[n][kt] = pwx2[(size_t)(kt * 20 + (5 * w + n)) * 64 + l];

  float bb[5];
#pragma unroll
  for (int n = 0; n < 5; ++n) {
    int j = 16 * (5 * w + n) + m;
    bb[n] = (j < 300) ? b1[j] : 0.f;
  }
  // zero the ENTIRE At buffer once (covers K-pad cols 300..327; R2 bug: only 300..313
  // were zeroed while A-frag reads reach col 319 -> uninitialized LDS -> NaN)
  {
    unsigned int* a32 = (unsigned int*)(&At[0]);
    for (int idx = tid; idx < 16 * HSTRIDE / 2; idx += 256) a32[idx] = 0u;
  }

  for (int mt = 0; mt < 4; ++mt) {
    const int vbase = blockIdx.x * 64 + mt * 16;
    __syncthreads();  // previous iteration's At readers (and the zeroing) done
#pragma unroll
    for (int q = 0; q < 5; ++q) {
      int idx = tid + 256 * q;
      if (idx < 1200) {
        int i = idx / 75, cc = idx % 75;
        float4 v = *(const float4*)(emb + (size_t)(vbase + i) * 300 + cc * 4);
        f16x4 fr = {(_Float16)v.x, (_Float16)v.y, (_Float16)v.z, (_Float16)v.w};
        *(f16x4*)(&At[i * HSTRIDE + cc * 4]) = fr;
      }
    }
    __syncthreads();
    f32x4 c[5];
#pragma unroll
    for (int n = 0; n < 5; ++n) c[n] = (f32x4){0.f, 0.f, 0.f, 0.f};
#pragma unroll
    for (int kt = 0; kt < 10; ++kt) {
      f16x8 a = *(const f16x8*)(&At[m * HSTRIDE + kt * 32 + g * 8]);
#pragma unroll
      for (int n = 0; n < 5; ++n) c[n] = mfma16(a, bw[n][kt], c[n]);
    }
#pragma unroll
    for (int n = 0; n < 5; ++n) {
      int j = 16 * (5 * w + n) + m;
      if (j < 300) {
#pragma unroll
        for (int r = 0; r < 4; ++r) {
          int v = vbase + 4 * g + r;
          premb[(size_t)v * 300 + j] = (_Float16)(c[n][r] + bb[n]);
        }
      }
    }
  }
}

// ---------------- phase2: the recurrence ----------------
__global__ __launch_bounds__(256, 1) void rnn_phase2(const int* __restrict__ x,
                                                     unsigned char* __restrict__ ws) {
  __shared__ _Float16 Hb[2][16 * HSTRIDE];
  const int tid = threadIdx.x;
  const int w = tid >> 6, l = tid & 63, g = l >> 4, m = l & 15;
  const int blk = blockIdx.x;
  const f16x8* pwh2 = (const f16x8*)(ws + OFF_PW2H);
  const _Float16* premb = (const _Float16*)(ws + OFF_PREMB);
  unsigned int* hall = (unsigned int*)(ws + OFF_HALL);

  f16x8 bw[5][10];
#pragma unroll
  for (int n = 0; n < 5; ++n)
#pragma unroll
    for (int kt = 0; kt < 10; ++kt)
      bw[n][kt] = pwh2[(size_t)(kt * 20 + (5 * w + n)) * 64 + l];

  int jn[5], jv[5];
#pragma unroll
  for (int n = 0; n < 5; ++n) {
    jn[n] = 16 * (5 * w + n) + m;
    jv[n] = (jn[n] < 300) ? 1 : 0;
  }

  // zero both H buffers (h0 = 0, plus K-pad columns)
  {
    unsigned int* hb32 = (unsigned int*)(&Hb[0][0]);
    for (int idx = tid; idx < 2 * 16 * HSTRIDE / 2; idx += 256) hb32[idx] = 0u;
  }
  // tokens for t=0
  int tok[4];
#pragma unroll
  for (int r = 0; r < 4; ++r) tok[r] = x[(size_t)(blk * 16 + 4 * g + r) * NT + 0];
  __syncthreads();

  for (int t = 0; t < NT; ++t) {
    // premb gather for this step (issued early, consumed in epilogue)
    _Float16 pr[5][4];
#pragma unroll
    for (int n = 0; n < 5; ++n)
#pragma unroll
      for (int r = 0; r < 4; ++r)
        pr[n][r] = jv[n] ? premb[(size_t)tok[r] * 300 + jn[n]] : (_Float16)0.f;
    // prefetch next step's tokens
    int tokn[4];
    {
      int tt = (t < NT - 1) ? t + 1 : NT - 1;
#pragma unroll
      for (int r = 0; r < 4; ++r) tokn[r] = x[(size_t)(blk * 16 + 4 * g + r) * NT + tt];
    }

    const _Float16* Hp = &Hb[t & 1][0];
    _Float16* Hn = &Hb[1 - (t & 1)][0];

    f32x4 c[5];
#pragma unroll
    for (int n = 0; n < 5; ++n) c[n] = (f32x4){0.f, 0.f, 0.f, 0.f};
#pragma unroll
    for (int kt = 0; kt < 10; ++kt) {
      f16x8 a = *(const f16x8*)(Hp + m * HSTRIDE + kt * 32 + g * 8);
#pragma unroll
      for (int n = 0; n < 5; ++n) c[n] = mfma16(a, bw[n][kt], c[n]);
    }

    // stream h_{t-1} (same buffer as A-reads) to hall, coalesced dwordx4
    if (t > 0) {
#pragma unroll
      for (int q = 0; q < 3; ++q) {
        int idx = tid + 256 * q;
        if (idx < 608) {
          int i = idx / 38, cc = idx % 38;
          uint4 d = *(const uint4*)(Hp + i * HSTRIDE + cc * 8);
          *(uint4*)(hall + ((size_t)(blk * 16 + i) * NT + (t - 1)) * 152 + cc * 4) = d;
        }
      }
    }

    // epilogue: h = sigmoid(C + premb), write f16 to the other buffer
#pragma unroll
    for (int n = 0; n < 5; ++n) {
#pragma unroll
      for (int r = 0; r < 4; ++r) {
        float val = c[n][r] + (float)pr[n][r];
        float ex = __expf(-val);
        float h = __builtin_amdgcn_rcpf(1.f + ex);
        Hn[(4 * g + r) * HSTRIDE + jn[n]] = (_Float16)h;
      }
    }
#pragma unroll
    for (int r = 0; r < 4; ++r) tok[r] = tokn[r];
    __syncthreads();
  }
  // final h_{511} lives in Hb[0]
#pragma unroll
  for (int q = 0; q < 3; ++q) {
    int idx = tid + 256 * q;
    if (idx < 608) {
      int i = idx / 38, cc = idx % 38;
      uint4 d = *(const uint4*)(&Hb[0][0] + i * HSTRIDE + cc * 8);
      *(uint4*)(hall + ((size_t)(blk * 16 + i) * NT + (NT - 1)) * 152 + cc * 4) = d;
    }
  }
}

// ---------------- phase3: out = h @ W23 + b23 ----------------
typedef _Float16 half2v __attribute__((ext_vector_type(2)));

__global__ __launch_bounds__(256) void rnn_phase3(const unsigned char* __restrict__ ws,
                                                  float* __restrict__ out) {
  int gw = (blockIdx.x * 256 + threadIdx.x) >> 6;  // one wave per (b,t) row
  int lane = threadIdx.x & 63;
  const unsigned int* hall = (const unsigned int*)(ws + OFF_HALL);
  const float* w23 = (const float*)(ws + OFF_W23);
  const float* b23 = (const float*)(ws + OFF_B23);
  const unsigned int* hr = hall + (size_t)gw * 152u;
  unsigned int h0 = hr[lane];
  unsigned int h1 = hr[64 + lane];
  unsigned int h2 = (lane < 22) ? hr[128 + lane] : 0u;
  float s0 = 0.f, s1 = 0.f;
  {
    int p = lane;
    half2v hv = __builtin_bit_cast(half2v, h0);
    float e0 = (float)hv.x, e1 = (float)hv.y;
    s0 += e0 * w23[(2 * p) * 2 + 0] + e1 * w23[(2 * p + 1) * 2 + 0];
    s1 += e0 * w23[(2 * p) * 2 + 1] + e1 * w23[(2 * p + 1) * 2 + 1];
  }
  {
    int p = 64 + lane;
    half2v hv = __builtin_bit_cast(half2v, h1);
    float e0 = (float)hv.x, e1 = (float)hv.y;
    s0 += e0 * w23[(2 * p) * 2 + 0] + e1 * w23[(2 * p + 1) * 2 + 0];
    s1 += e0 * w23[(2 * p) * 2 + 1] + e1 * w23[(2 * p + 1) * 2 + 1];
  }
  if (lane < 22) {
    int p = 128 + lane;
    half2v hv = __builtin_bit_cast(half2v, h2);
    float e0 = (float)hv.x, e1 = (float)hv.y;
    s0 += e0 * w23[(2 * p) * 2 + 0] + e1 * w23[(2 * p + 1) * 2 + 0];
    s1 += e0 * w23[(2 * p) * 2 + 1] + e1 * w23[(2 * p + 1) * 2 + 1];
  }
  for (int mmask = 32; mmask; mmask >>= 1) {
    s0 += __shfl_xor(s0, mmask, 64);
    s1 += __shfl_xor(s1, mmask, 64);
  }
  if (lane == 0) {
    float2 o;
    o.x = s0 + b23[0];
    o.y = s1 + b23[1];
    *(float2*)(out + (size_t)gw * 2) = o;
  }
}

extern "C" void kernel_launch(void* const* d_in, const int* in_sizes, int n_in,
                              void* d_out, int out_size, void* d_ws, size_t ws_size,
                              hipStream_t stream) {
  const int* x = (const int*)d_in[0];
  const float* emb = (const float*)d_in[1];
  const float* W1 = (const float*)d_in[2];
  const float* b1 = (const float*)d_in[3];
  const float* W2 = (const float*)d_in[4];
  const float* b2 = (const float*)d_in[5];
  const float* W3 = (const float*)d_in[6];
  const float* b3 = (const float*)d_in[7];
  unsigned char* ws = (unsigned char*)d_ws;
  float* out = (float*)d_out;

  hipLaunchKernelGGL(rnn_prep, dim3(802), dim3(256), 0, stream, W1, W2, b2, W3, b3, ws);
  hipLaunchKernelGGL(rnn_phase1, dim3(500), dim3(256), 0, stream, emb, b1, ws);
  hipLaunchKernelGGL(rnn_phase2, dim3(8), dim3(256), 0, stream, x, ws);
  hipLaunchKernelGGL(rnn_phase3, dim3(16384), dim3(256), 0, stream, ws, out);
}

// Round 4
// 1409.775 us; speedup vs baseline: 1.7699x; 1.7699x over previous
//
#include <hip/hip_runtime.h>
#include <hip/hip_fp16.h>

// Elman RNN via MFMA (R4: 8-wave phase2, register-pressure fix):
//   prep:   pack W1x/W1h into 16x16x32 B-fragment tables; W23=W2@W3, b23=b2@W3+b3
//   phase1: premb[v][j] = f16( emb[v]@W1x + b1 )  -- MFMA GEMM, 500 blocks x 64 rows
//   phase2: 8 blocks x 16 batches, 512 thr / 8 waves, j-split {3,3,3,3,2,2,2,2} jt.
//           bw frags <=120 VGPR -> gathers stay pipelined. h stored f16 direct to hall.
//   phase3: out = h @ W23 + b23 (one wave per (b,t) row)

typedef _Float16 f16x8 __attribute__((ext_vector_type(8)));
typedef _Float16 f16x4 __attribute__((ext_vector_type(4)));
typedef float f32x4 __attribute__((ext_vector_type(4)));

#define NVOCAB 32000
#define NB 128
#define NT 512

// workspace byte offsets
#define OFF_PREMB 0ull                 // f16 [32000][300]            = 19,200,000
#define OFF_HALL  19200000ull          // u16 [65536][304]            = 39,845,888
#define OFF_PW2X  59045888ull          // f16 frag table [10][20][64][8] = 204,800
#define OFF_PW2H  59250688ull          // f16 frag table                 = 204,800
#define OFF_W23   59455488ull          // f32 [300][2]                =      2,400
#define OFF_B23   59457888ull          // f32 [2]

#define HSTRIDE 328                    // halves per H-tile row (656B, 16B-aligned)

__device__ __forceinline__ f32x4 mfma16(f16x8 a, f16x8 b, f32x4 c) {
  return __builtin_amdgcn_mfma_f32_16x16x32_f16(a, b, c, 0, 0, 0);
}

__device__ __forceinline__ float u16tof(unsigned short u) {
  _Float16 hf = __builtin_bit_cast(_Float16, u);
  return (float)hf;
}

// ---------------- prep: fragment tables + W23/b23 ----------------
// B-frag convention: element e of lane l holds W[k=32*kt+8*(l/16)+e][j=16*jt+(l%16)],
// zero-padded outside 300x300.
__global__ __launch_bounds__(256) void rnn_prep(const float* __restrict__ W1,
                                                const float* __restrict__ W2,
                                                const float* __restrict__ b2,
                                                const float* __restrict__ W3,
                                                const float* __restrict__ b3,
                                                unsigned char* __restrict__ ws) {
  unsigned int tid = blockIdx.x * 256 + threadIdx.x;
  if (tid < 204800u) {
    int part = tid / 102400;          // 0 = W1x (k rows 0..299), 1 = W1h (rows 300..599)
    int f = tid % 102400;
    int e = f & 7, l = (f >> 3) & 63, jt = (f >> 9) % 20, kt = f / 10240;
    int g = l >> 4, m = l & 15;
    int k = 32 * kt + 8 * g + e;
    int j = 16 * jt + m;
    _Float16 val = (_Float16)0.f;
    if (k < 300 && j < 300) val = (_Float16)W1[(size_t)(part * 300 + k) * 300 + j];
    ((_Float16*)(ws + (part ? OFF_PW2H : OFF_PW2X)))[f] = val;
  } else if (tid < 205100u) {
    int j = tid - 204800;
    float s0 = 0.f, s1 = 0.f;
    for (int k = 0; k < 300; ++k) {
      float w = W2[j * 300 + k];
      s0 += w * W3[k * 2 + 0];
      s1 += w * W3[k * 2 + 1];
    }
    float* w23 = (float*)(ws + OFF_W23);
    w23[j * 2 + 0] = s0;
    w23[j * 2 + 1] = s1;
  } else if (tid == 205100u) {
    float s0 = b3[0], s1 = b3[1];
    for (int k = 0; k < 300; ++k) {
      s0 += b2[k] * W3[k * 2 + 0];
      s1 += b2[k] * W3[k * 2 + 1];
    }
    float* b23 = (float*)(ws + OFF_B23);
    b23[0] = s0; b23[1] = s1;
  }
}

// ---------------- phase1: premb = f16(emb @ W1x + b1) ----------------
__global__ __launch_bounds__(256, 1) void rnn_phase1(const float* __restrict__ emb,
                                                     const float* __restrict__ b1,
                                                     unsigned char* __restrict__ ws) {
  __shared__ _Float16 At[16 * HSTRIDE];
  const int tid = threadIdx.x;
  const int w = tid >> 6, l = tid & 63, g = l >> 4, m = l & 15;
  const f16x8* pwx2 = (const f16x8*)(ws + OFF_PW2X);
  _Float16* premb = (_Float16*)(ws + OFF_PREMB);

  f16x8 bw[5][10];
#pragma unroll
  for (int n = 0; n < 5; ++n)
#pragma unroll
    for (int kt = 0; kt < 10; ++kt)
      bw[n][kt] = pwx2[(size_t)(kt * 20 + (5 * w + n)) * 64 + l];

  float bb[5];
#pragma unroll
  for (int n = 0; n < 5; ++n) {
    int j = 16 * (5 * w + n) + m;
    bb[n] = (j < 300) ? b1[j] : 0.f;
  }
  // zero the ENTIRE At buffer once (K-pad cols 300..327 must be zero for kt=9)
  {
    unsigned int* a32 = (unsigned int*)(&At[0]);
    for (int idx = tid; idx < 16 * HSTRIDE / 2; idx += 256) a32[idx] = 0u;
  }

  for (int mt = 0; mt < 4; ++mt) {
    const int vbase = blockIdx.x * 64 + mt * 16;
    __syncthreads();  // previous iteration's At readers (and the zeroing) done
#pragma unroll
    for (int q = 0; q < 5; ++q) {
      int idx = tid + 256 * q;
      if (idx < 1200) {
        int i = idx / 75, cc = idx % 75;
        float4 v = *(const float4*)(emb + (size_t)(vbase + i) * 300 + cc * 4);
        f16x4 fr = {(_Float16)v.x, (_Float16)v.y, (_Float16)v.z, (_Float16)v.w};
        *(f16x4*)(&At[i * HSTRIDE + cc * 4]) = fr;
      }
    }
    __syncthreads();
    f32x4 c[5];
#pragma unroll
    for (int n = 0; n < 5; ++n) c[n] = (f32x4){0.f, 0.f, 0.f, 0.f};
#pragma unroll
    for (int kt = 0; kt < 10; ++kt) {
      f16x8 a = *(const f16x8*)(&At[m * HSTRIDE + kt * 32 + g * 8]);
#pragma unroll
      for (int n = 0; n < 5; ++n) c[n] = mfma16(a, bw[n][kt], c[n]);
    }
#pragma unroll
    for (int n = 0; n < 5; ++n) {
      int j = 16 * (5 * w + n) + m;
      if (j < 300) {
#pragma unroll
        for (int r = 0; r < 4; ++r) {
          int v = vbase + 4 * g + r;
          premb[(size_t)v * 300 + j] = (_Float16)(c[n][r] + bb[n]);
        }
      }
    }
  }
}

// ---------------- phase2: the recurrence (8 waves, j-split) ----------------
__global__ __launch_bounds__(512, 2) void rnn_phase2(const int* __restrict__ x,
                                                     unsigned char* __restrict__ ws) {
  __shared__ _Float16 Hb[2][16 * HSTRIDE];
  const int tid = threadIdx.x;
  const int w = tid >> 6, l = tid & 63, g = l >> 4, m = l & 15;
  const int blk = blockIdx.x;
  const int ncnt = (w < 4) ? 3 : 2;                 // waves 0-3: 3 j-tiles, 4-7: 2
  const int jt0 = (w < 4) ? 3 * w : 12 + 2 * (w - 4);
  const f16x8* pwh2 = (const f16x8*)(ws + OFF_PW2H);
  const unsigned short* premb = (const unsigned short*)(ws + OFF_PREMB);
  unsigned short* hall = (unsigned short*)(ws + OFF_HALL);

  f16x8 bw[3][10];                                  // <=120 VGPRs (R3 bug: 200 -> AGPR spill)
#pragma unroll
  for (int n = 0; n < 3; ++n)
    if (n < ncnt)
#pragma unroll
      for (int kt = 0; kt < 10; ++kt)
        bw[n][kt] = pwh2[(size_t)(kt * 20 + (jt0 + n)) * 64 + l];

  int jn[3], jv[3];
#pragma unroll
  for (int n = 0; n < 3; ++n) {
    jn[n] = 16 * (jt0 + n) + m;
    jv[n] = (n < ncnt && jn[n] < 300) ? 1 : 0;
  }

  // zero both H buffers (h0 = 0, plus K-pad columns)
  {
    unsigned int* hb32 = (unsigned int*)(&Hb[0][0]);
    for (int idx = tid; idx < 2 * 16 * HSTRIDE / 2; idx += 512) hb32[idx] = 0u;
  }
  int tok[4];
#pragma unroll
  for (int r = 0; r < 4; ++r) tok[r] = x[(blk * 16 + 4 * g + r) * NT + 0];
  __syncthreads();

  for (int t = 0; t < NT; ++t) {
    // premb gather for this step (issued early, waited in epilogue)
    unsigned short pru[3][4];
#pragma unroll
    for (int n = 0; n < 3; ++n)
#pragma unroll
      for (int r = 0; r < 4; ++r)
        pru[n][r] = jv[n] ? premb[(size_t)tok[r] * 300 + jn[n]] : (unsigned short)0;
    // prefetch next step's tokens (L1-resident line)
    int tokn[4];
    {
      int tt = (t < NT - 1) ? t + 1 : NT - 1;
#pragma unroll
      for (int r = 0; r < 4; ++r) tokn[r] = x[(blk * 16 + 4 * g + r) * NT + tt];
    }

    const _Float16* Hp = &Hb[t & 1][0];
    _Float16* Hn = &Hb[1 - (t & 1)][0];

    f32x4 c[3];
#pragma unroll
    for (int n = 0; n < 3; ++n) c[n] = (f32x4){0.f, 0.f, 0.f, 0.f};
#pragma unroll
    for (int kt = 0; kt < 10; ++kt) {
      f16x8 a = *(const f16x8*)(Hp + m * HSTRIDE + kt * 32 + g * 8);
#pragma unroll
      for (int n = 0; n < 3; ++n)
        if (n < ncnt) c[n] = mfma16(a, bw[n][kt], c[n]);
    }

    // epilogue: h = sigmoid(C + premb); write f16 to next H buffer AND to hall
#pragma unroll
    for (int n = 0; n < 3; ++n) {
      if (jv[n]) {
#pragma unroll
        for (int r = 0; r < 4; ++r) {
          float val = c[n][r] + u16tof(pru[n][r]);
          float ex = __expf(-val);
          float h = __builtin_amdgcn_rcpf(1.f + ex);
          _Float16 hf = (_Float16)h;
          Hn[(4 * g + r) * HSTRIDE + jn[n]] = hf;
          hall[((size_t)(blk * 16 + 4 * g + r) * NT + t) * 304 + jn[n]] =
              __builtin_bit_cast(unsigned short, hf);
        }
      }
    }
#pragma unroll
    for (int r = 0; r < 4; ++r) tok[r] = tokn[r];
    __syncthreads();
  }
}

// ---------------- phase3: out = h @ W23 + b23 ----------------
typedef _Float16 half2v __attribute__((ext_vector_type(2)));

__global__ __launch_bounds__(256) void rnn_phase3(const unsigned char* __restrict__ ws,
                                                  float* __restrict__ out) {
  int gw = (blockIdx.x * 256 + threadIdx.x) >> 6;  // one wave per (b,t) row
  int lane = threadIdx.x & 63;
  const unsigned int* hall = (const unsigned int*)(ws + OFF_HALL);
  const float* w23 = (const float*)(ws + OFF_W23);
  const float* b23 = (const float*)(ws + OFF_B23);
  const unsigned int* hr = hall + (size_t)gw * 152u;   // 152 u32 = 304 halves per row
  unsigned int h0 = hr[lane];
  unsigned int h1 = hr[64 + lane];
  unsigned int h2 = (lane < 22) ? hr[128 + lane] : 0u; // pairs 128..149 -> j 256..299
  float s0 = 0.f, s1 = 0.f;
  {
    int p = lane;
    half2v hv = __builtin_bit_cast(half2v, h0);
    float e0 = (float)hv.x, e1 = (float)hv.y;
    s0 += e0 * w23[(2 * p) * 2 + 0] + e1 * w23[(2 * p + 1) * 2 + 0];
    s1 += e0 * w23[(2 * p) * 2 + 1] + e1 * w23[(2 * p + 1) * 2 + 1];
  }
  {
    int p = 64 + lane;
    half2v hv = __builtin_bit_cast(half2v, h1);
    float e0 = (float)hv.x, e1 = (float)hv.y;
    s0 += e0 * w23[(2 * p) * 2 + 0] + e1 * w23[(2 * p + 1) * 2 + 0];
    s1 += e0 * w23[(2 * p) * 2 + 1] + e1 * w23[(2 * p + 1) * 2 + 1];
  }
  if (lane < 22) {
    int p = 128 + lane;
    half2v hv = __builtin_bit_cast(half2v, h2);
    float e0 = (float)hv.x, e1 = (float)hv.y;
    s0 += e0 * w23[(2 * p) * 2 + 0] + e1 * w23[(2 * p + 1) * 2 + 0];
    s1 += e0 * w23[(2 * p) * 2 + 1] + e1 * w23[(2 * p + 1) * 2 + 1];
  }
  for (int mmask = 32; mmask; mmask >>= 1) {
    s0 += __shfl_xor(s0, mmask, 64);
    s1 += __shfl_xor(s1, mmask, 64);
  }
  if (lane == 0) {
    float2 o;
    o.x = s0 + b23[0];
    o.y = s1 + b23[1];
    *(float2*)(out + (size_t)gw * 2) = o;
  }
}

extern "C" void kernel_launch(void* const* d_in, const int* in_sizes, int n_in,
                              void* d_out, int out_size, void* d_ws, size_t ws_size,
                              hipStream_t stream) {
  const int* x = (const int*)d_in[0];
  const float* emb = (const float*)d_in[1];
  const float* W1 = (const float*)d_in[2];
  const float* b1 = (const float*)d_in[3];
  const float* W2 = (const float*)d_in[4];
  const float* b2 = (const float*)d_in[5];
  const float* W3 = (const float*)d_in[6];
  const float* b3 = (const float*)d_in[7];
  unsigned char* ws = (unsigned char*)d_ws;
  float* out = (float*)d_out;

  hipLaunchKernelGGL(rnn_prep, dim3(802), dim3(256), 0, stream, W1, W2, b2, W3, b3, ws);
  hipLaunchKernelGGL(rnn_phase1, dim3(500), dim3(256), 0, stream, emb, b1, ws);
  hipLaunchKernelGGL(rnn_phase2, dim3(8), dim3(512), 0, stream, x, ws);
  hipLaunchKernelGGL(rnn_phase3, dim3(16384), dim3(256), 0, stream, ws, out);
}

// Round 5
// 1131.004 us; speedup vs baseline: 2.2061x; 1.2465x over previous
//
#include <hip/hip_runtime.h>
#include <hip/hip_fp16.h>

// Elman RNN via MFMA (R5):
//   - launch_bounds(512,1): full VGPR budget (grid=8 blocks, occupancy moot)
//   - premb gather pipelined one full step ahead (covers HBM-miss latency)
//   - raw s_barrier + lgkmcnt(0) only: global h-stores are fire-and-forget,
//     no vmcnt(0) drain per step (that drain was ~500 cyc/step in R4)

typedef _Float16 f16x8 __attribute__((ext_vector_type(8)));
typedef _Float16 f16x4 __attribute__((ext_vector_type(4)));
typedef float f32x4 __attribute__((ext_vector_type(4)));

#define NVOCAB 32000
#define NB 128
#define NT 512

// workspace byte offsets
#define OFF_PREMB 0ull                 // f16 [32000][300]            = 19,200,000
#define OFF_HALL  19200000ull          // u16 [65536][304]            = 39,845,888
#define OFF_PW2X  59045888ull          // f16 frag table [10][20][64][8] = 204,800
#define OFF_PW2H  59250688ull          // f16 frag table                 = 204,800
#define OFF_W23   59455488ull          // f32 [300][2]                =      2,400
#define OFF_B23   59457888ull          // f32 [2]

#define HSTRIDE 328                    // halves per H-tile row (656B, 16B-aligned)

__device__ __forceinline__ f32x4 mfma16(f16x8 a, f16x8 b, f32x4 c) {
  return __builtin_amdgcn_mfma_f32_16x16x32_f16(a, b, c, 0, 0, 0);
}

__device__ __forceinline__ float u16tof(unsigned short u) {
  _Float16 hf = __builtin_bit_cast(_Float16, u);
  return (float)hf;
}

// barrier that waits ONLY LDS ops (recurrence visibility), leaves global
// stores/loads in flight. __syncthreads would add s_waitcnt vmcnt(0).
__device__ __forceinline__ void barrier_lgkm() {
  asm volatile("s_waitcnt lgkmcnt(0)\n\ts_barrier" ::: "memory");
}

// ---------------- prep: fragment tables + W23/b23 ----------------
// B-frag convention: element e of lane l holds W[k=32*kt+8*(l/16)+e][j=16*jt+(l%16)],
// zero-padded outside 300x300.
__global__ __launch_bounds__(256) void rnn_prep(const float* __restrict__ W1,
                                                const float* __restrict__ W2,
                                                const float* __restrict__ b2,
                                                const float* __restrict__ W3,
                                                const float* __restrict__ b3,
                                                unsigned char* __restrict__ ws) {
  unsigned int tid = blockIdx.x * 256 + threadIdx.x;
  if (tid < 204800u) {
    int part = tid / 102400;          // 0 = W1x (k rows 0..299), 1 = W1h (rows 300..599)
    int f = tid % 102400;
    int e = f & 7, l = (f >> 3) & 63, jt = (f >> 9) % 20, kt = f / 10240;
    int g = l >> 4, m = l & 15;
    int k = 32 * kt + 8 * g + e;
    int j = 16 * jt + m;
    _Float16 val = (_Float16)0.f;
    if (k < 300 && j < 300) val = (_Float16)W1[(size_t)(part * 300 + k) * 300 + j];
    ((_Float16*)(ws + (part ? OFF_PW2H : OFF_PW2X)))[f] = val;
  } else if (tid < 205100u) {
    int j = tid - 204800;
    float s0 = 0.f, s1 = 0.f;
    for (int k = 0; k < 300; ++k) {
      float w = W2[j * 300 + k];
      s0 += w * W3[k * 2 + 0];
      s1 += w * W3[k * 2 + 1];
    }
    float* w23 = (float*)(ws + OFF_W23);
    w23[j * 2 + 0] = s0;
    w23[j * 2 + 1] = s1;
  } else if (tid == 205100u) {
    float s0 = b3[0], s1 = b3[1];
    for (int k = 0; k < 300; ++k) {
      s0 += b2[k] * W3[k * 2 + 0];
      s1 += b2[k] * W3[k * 2 + 1];
    }
    float* b23 = (float*)(ws + OFF_B23);
    b23[0] = s0; b23[1] = s1;
  }
}

// ---------------- phase1: premb = f16(emb @ W1x + b1) ----------------
__global__ __launch_bounds__(256, 1) void rnn_phase1(const float* __restrict__ emb,
                                                     const float* __restrict__ b1,
                                                     unsigned char* __restrict__ ws) {
  __shared__ _Float16 At[16 * HSTRIDE];
  const int tid = threadIdx.x;
  const int w = tid >> 6, l = tid & 63, g = l >> 4, m = l & 15;
  const f16x8* pwx2 = (const f16x8*)(ws + OFF_PW2X);
  _Float16* premb = (_Float16*)(ws + OFF_PREMB);

  f16x8 bw[5][10];
#pragma unroll
  for (int n = 0; n < 5; ++n)
#pragma unroll
    for (int kt = 0; kt < 10; ++kt)
      bw[n][kt] = pwx2[(size_t)(kt * 20 + (5 * w + n)) * 64 + l];

  float bb[5];
#pragma unroll
  for (int n = 0; n < 5; ++n) {
    int j = 16 * (5 * w + n) + m;
    bb[n] = (j < 300) ? b1[j] : 0.f;
  }
  // zero the ENTIRE At buffer once (K-pad cols 300..327 must be zero for kt=9)
  {
    unsigned int* a32 = (unsigned int*)(&At[0]);
    for (int idx = tid; idx < 16 * HSTRIDE / 2; idx += 256) a32[idx] = 0u;
  }

  for (int mt = 0; mt < 4; ++mt) {
    const int vbase = blockIdx.x * 64 + mt * 16;
    __syncthreads();  // previous iteration's At readers (and the zeroing) done
#pragma unroll
    for (int q = 0; q < 5; ++q) {
      int idx = tid + 256 * q;
      if (idx < 1200) {
        int i = idx / 75, cc = idx % 75;
        float4 v = *(const float4*)(emb + (size_t)(vbase + i) * 300 + cc * 4);
        f16x4 fr = {(_Float16)v.x, (_Float16)v.y, (_Float16)v.z, (_Float16)v.w};
        *(f16x4*)(&At[i * HSTRIDE + cc * 4]) = fr;
      }
    }
    __syncthreads();
    f32x4 c[5];
#pragma unroll
    for (int n = 0; n < 5; ++n) c[n] = (f32x4){0.f, 0.f, 0.f, 0.f};
#pragma unroll
    for (int kt = 0; kt < 10; ++kt) {
      f16x8 a = *(const f16x8*)(&At[m * HSTRIDE + kt * 32 + g * 8]);
#pragma unroll
      for (int n = 0; n < 5; ++n) c[n] = mfma16(a, bw[n][kt], c[n]);
    }
#pragma unroll
    for (int n = 0; n < 5; ++n) {
      int j = 16 * (5 * w + n) + m;
      if (j < 300) {
#pragma unroll
        for (int r = 0; r < 4; ++r) {
          int v = vbase + 4 * g + r;
          premb[(size_t)v * 300 + j] = (_Float16)(c[n][r] + bb[n]);
        }
      }
    }
  }
}

// ---------------- phase2: the recurrence (8 waves, j-split, pipelined gather) ----------------
__global__ __launch_bounds__(512, 1) void rnn_phase2(const int* __restrict__ x,
                                                     unsigned char* __restrict__ ws) {
  __shared__ _Float16 Hb[2][16 * HSTRIDE];
  const int tid = threadIdx.x;
  const int w = tid >> 6, l = tid & 63, g = l >> 4, m = l & 15;
  const int blk = blockIdx.x;
  const int ncnt = (w < 4) ? 3 : 2;                 // waves 0-3: 3 j-tiles, 4-7: 2
  const int jt0 = (w < 4) ? 3 * w : 12 + 2 * (w - 4);
  const f16x8* pwh2 = (const f16x8*)(ws + OFF_PW2H);
  const unsigned short* premb = (const unsigned short*)(ws + OFF_PREMB);
  unsigned short* hall = (unsigned short*)(ws + OFF_HALL);

  f16x8 bw[3][10];                                  // 120 VGPRs; (512,1) gives headroom
#pragma unroll
  for (int n = 0; n < 3; ++n)
    if (n < ncnt)
#pragma unroll
      for (int kt = 0; kt < 10; ++kt)
        bw[n][kt] = pwh2[(size_t)(kt * 20 + (jt0 + n)) * 64 + l];

  int jn[3], jv[3];
#pragma unroll
  for (int n = 0; n < 3; ++n) {
    jn[n] = 16 * (jt0 + n) + m;
    jv[n] = (n < ncnt && jn[n] < 300) ? 1 : 0;
  }

  // zero both H buffers (h0 = 0, plus K-pad columns)
  {
    unsigned int* hb32 = (unsigned int*)(&Hb[0][0]);
    for (int idx = tid; idx < 2 * 16 * HSTRIDE / 2; idx += 512) hb32[idx] = 0u;
  }

  // gather pipeline prologue: pru = premb rows for step 0; tok = tokens for step 1
  int tok[4];
#pragma unroll
  for (int r = 0; r < 4; ++r) tok[r] = x[(blk * 16 + 4 * g + r) * NT + 0];
  unsigned short pru[3][4];
#pragma unroll
  for (int n = 0; n < 3; ++n)
#pragma unroll
    for (int r = 0; r < 4; ++r)
      pru[n][r] = jv[n] ? premb[(size_t)tok[r] * 300 + jn[n]] : (unsigned short)0;
#pragma unroll
  for (int r = 0; r < 4; ++r) tok[r] = x[(blk * 16 + 4 * g + r) * NT + 1];
  __syncthreads();

  for (int t = 0; t < NT; ++t) {
    // issue gathers for step t+1 (consumed next iteration -> full step of slack)
    unsigned short prn[3][4];
#pragma unroll
    for (int n = 0; n < 3; ++n)
#pragma unroll
      for (int r = 0; r < 4; ++r)
        prn[n][r] = jv[n] ? premb[(size_t)tok[r] * 300 + jn[n]] : (unsigned short)0;
    // prefetch tokens for step t+2 (L1-resident)
    {
      int tt = (t < NT - 2) ? t + 2 : NT - 1;
#pragma unroll
      for (int r = 0; r < 4; ++r) tok[r] = x[(blk * 16 + 4 * g + r) * NT + tt];
    }

    const _Float16* Hp = &Hb[t & 1][0];
    _Float16* Hn = &Hb[1 - (t & 1)][0];

    f32x4 c[3];
#pragma unroll
    for (int n = 0; n < 3; ++n) c[n] = (f32x4){0.f, 0.f, 0.f, 0.f};
#pragma unroll
    for (int kt = 0; kt < 10; ++kt) {
      f16x8 a = *(const f16x8*)(Hp + m * HSTRIDE + kt * 32 + g * 8);
#pragma unroll
      for (int n = 0; n < 3; ++n)
        if (n < ncnt) c[n] = mfma16(a, bw[n][kt], c[n]);
    }

    // epilogue: h = sigmoid(C + premb); LDS write first (barrier waits lgkm only),
    // then fire-and-forget global stores
    _Float16 hf[3][4];
#pragma unroll
    for (int n = 0; n < 3; ++n) {
      if (jv[n]) {
#pragma unroll
        for (int r = 0; r < 4; ++r) {
          float val = c[n][r] + u16tof(pru[n][r]);
          float ex = __expf(-val);
          float h = __builtin_amdgcn_rcpf(1.f + ex);
          hf[n][r] = (_Float16)h;
          Hn[(4 * g + r) * HSTRIDE + jn[n]] = hf[n][r];
        }
      }
    }
#pragma unroll
    for (int n = 0; n < 3; ++n) {
      if (jv[n]) {
#pragma unroll
        for (int r = 0; r < 4; ++r)
          hall[((size_t)(blk * 16 + 4 * g + r) * NT + t) * 304 + jn[n]] =
              __builtin_bit_cast(unsigned short, hf[n][r]);
      }
    }
#pragma unroll
    for (int n = 0; n < 3; ++n)
#pragma unroll
      for (int r = 0; r < 4; ++r) pru[n][r] = prn[n][r];
    barrier_lgkm();
  }
}

// ---------------- phase3: out = h @ W23 + b23 ----------------
typedef _Float16 half2v __attribute__((ext_vector_type(2)));

__global__ __launch_bounds__(256) void rnn_phase3(const unsigned char* __restrict__ ws,
                                                  float* __restrict__ out) {
  int gw = (blockIdx.x * 256 + threadIdx.x) >> 6;  // one wave per (b,t) row
  int lane = threadIdx.x & 63;
  const unsigned int* hall = (const unsigned int*)(ws + OFF_HALL);
  const float* w23 = (const float*)(ws + OFF_W23);
  const float* b23 = (const float*)(ws + OFF_B23);
  const unsigned int* hr = hall + (size_t)gw * 152u;   // 152 u32 = 304 halves per row
  unsigned int h0 = hr[lane];
  unsigned int h1 = hr[64 + lane];
  unsigned int h2 = (lane < 22) ? hr[128 + lane] : 0u; // pairs 128..149 -> j 256..299
  float s0 = 0.f, s1 = 0.f;
  {
    int p = lane;
    half2v hv = __builtin_bit_cast(half2v, h0);
    float e0 = (float)hv.x, e1 = (float)hv.y;
    s0 += e0 * w23[(2 * p) * 2 + 0] + e1 * w23[(2 * p + 1) * 2 + 0];
    s1 += e0 * w23[(2 * p) * 2 + 1] + e1 * w23[(2 * p + 1) * 2 + 1];
  }
  {
    int p = 64 + lane;
    half2v hv = __builtin_bit_cast(half2v, h1);
    float e0 = (float)hv.x, e1 = (float)hv.y;
    s0 += e0 * w23[(2 * p) * 2 + 0] + e1 * w23[(2 * p + 1) * 2 + 0];
    s1 += e0 * w23[(2 * p) * 2 + 1] + e1 * w23[(2 * p + 1) * 2 + 1];
  }
  if (lane < 22) {
    int p = 128 + lane;
    half2v hv = __builtin_bit_cast(half2v, h2);
    float e0 = (float)hv.x, e1 = (float)hv.y;
    s0 += e0 * w23[(2 * p) * 2 + 0] + e1 * w23[(2 * p + 1) * 2 + 0];
    s1 += e0 * w23[(2 * p) * 2 + 1] + e1 * w23[(2 * p + 1) * 2 + 1];
  }
  for (int mmask = 32; mmask; mmask >>= 1) {
    s0 += __shfl_xor(s0, mmask, 64);
    s1 += __shfl_xor(s1, mmask, 64);
  }
  if (lane == 0) {
    float2 o;
    o.x = s0 + b23[0];
    o.y = s1 + b23[1];
    *(float2*)(out + (size_t)gw * 2) = o;
  }
}

extern "C" void kernel_launch(void* const* d_in, const int* in_sizes, int n_in,
                              void* d_out, int out_size, void* d_ws, size_t ws_size,
                              hipStream_t stream) {
  const int* x = (const int*)d_in[0];
  const float* emb = (const float*)d_in[1];
  const float* W1 = (const float*)d_in[2];
  const float* b1 = (const float*)d_in[3];
  const float* W2 = (const float*)d_in[4];
  const float* b2 = (const float*)d_in[5];
  const float* W3 = (const float*)d_in[6];
  const float* b3 = (const float*)d_in[7];
  unsigned char* ws = (unsigned char*)d_ws;
  float* out = (float*)d_out;

  hipLaunchKernelGGL(rnn_prep, dim3(802), dim3(256), 0, stream, W1, W2, b2, W3, b3, ws);
  hipLaunchKernelGGL(rnn_phase1, dim3(500), dim3(256), 0, stream, emb, b1, ws);
  hipLaunchKernelGGL(rnn_phase2, dim3(8), dim3(512), 0, stream, x, ws);
  hipLaunchKernelGGL(rnn_phase3, dim3(16384), dim3(256), 0, stream, ws, out);
}

// Round 6
// 771.328 us; speedup vs baseline: 3.2349x; 1.4663x over previous
//
#include <hip/hip_runtime.h>
#include <hip/hip_fp16.h>

// Elman RNN via MFMA (R6):
//   phase2 step loop has NO scattered global ops:
//   - premb rows for t+1 loaded coalesced (uint4) -> LDS double-buffer stage;
//     epilogue reads 12 values from LDS at immediate offsets
//   - h_t stored to hall by reading Hp back as b128 chunks -> dwordx4 stores
//   - raw lgkm-only barrier per step (global stores stay in flight)

typedef _Float16 f16x8 __attribute__((ext_vector_type(8)));
typedef _Float16 f16x4 __attribute__((ext_vector_type(4)));
typedef float f32x4 __attribute__((ext_vector_type(4)));

#define NVOCAB 32000
#define NB 128
#define NT 512

// workspace byte offsets (premb restrided to 304 halves/row)
#define OFF_PREMB 0ull                 // f16 [32000][304]            = 19,456,000
#define OFF_HALL  19456000ull          // u16 [65536][304]            = 39,845,888
#define OFF_PW2X  59301888ull          // f16 frag table [10][20][64][8] = 204,800
#define OFF_PW2H  59506688ull          // f16 frag table                 = 204,800
#define OFF_W23   59711488ull          // f32 [300][2]                =      2,400
#define OFF_B23   59713888ull          // f32 [2]

#define HSTRIDE 328                    // halves per H-tile row (656B, 16B-aligned)

__device__ __forceinline__ f32x4 mfma16(f16x8 a, f16x8 b, f32x4 c) {
  return __builtin_amdgcn_mfma_f32_16x16x32_f16(a, b, c, 0, 0, 0);
}

// barrier that waits ONLY LDS ops; global stores stay in flight
__device__ __forceinline__ void barrier_lgkm() {
  asm volatile("s_waitcnt lgkmcnt(0)\n\ts_barrier" ::: "memory");
}

// ---------------- prep: fragment tables + W23/b23 ----------------
// B-frag convention: element e of lane l holds W[k=32*kt+8*(l/16)+e][j=16*jt+(l%16)],
// zero-padded outside 300x300.
__global__ __launch_bounds__(256) void rnn_prep(const float* __restrict__ W1,
                                                const float* __restrict__ W2,
                                                const float* __restrict__ b2,
                                                const float* __restrict__ W3,
                                                const float* __restrict__ b3,
                                                unsigned char* __restrict__ ws) {
  unsigned int tid = blockIdx.x * 256 + threadIdx.x;
  if (tid < 204800u) {
    int part = tid / 102400;          // 0 = W1x (k rows 0..299), 1 = W1h (rows 300..599)
    int f = tid % 102400;
    int e = f & 7, l = (f >> 3) & 63, jt = (f >> 9) % 20, kt = f / 10240;
    int g = l >> 4, m = l & 15;
    int k = 32 * kt + 8 * g + e;
    int j = 16 * jt + m;
    _Float16 val = (_Float16)0.f;
    if (k < 300 && j < 300) val = (_Float16)W1[(size_t)(part * 300 + k) * 300 + j];
    ((_Float16*)(ws + (part ? OFF_PW2H : OFF_PW2X)))[f] = val;
  } else if (tid < 205100u) {
    int j = tid - 204800;
    float s0 = 0.f, s1 = 0.f;
    for (int k = 0; k < 300; ++k) {
      float w = W2[j * 300 + k];
      s0 += w * W3[k * 2 + 0];
      s1 += w * W3[k * 2 + 1];
    }
    float* w23 = (float*)(ws + OFF_W23);
    w23[j * 2 + 0] = s0;
    w23[j * 2 + 1] = s1;
  } else if (tid == 205100u) {
    float s0 = b3[0], s1 = b3[1];
    for (int k = 0; k < 300; ++k) {
      s0 += b2[k] * W3[k * 2 + 0];
      s1 += b2[k] * W3[k * 2 + 1];
    }
    float* b23 = (float*)(ws + OFF_B23);
    b23[0] = s0; b23[1] = s1;
  }
}

// ---------------- phase1: premb = f16(emb @ W1x + b1), stride 304 ----------------
__global__ __launch_bounds__(256, 1) void rnn_phase1(const float* __restrict__ emb,
                                                     const float* __restrict__ b1,
                                                     unsigned char* __restrict__ ws) {
  __shared__ _Float16 At[16 * HSTRIDE];
  const int tid = threadIdx.x;
  const int w = tid >> 6, l = tid & 63, g = l >> 4, m = l & 15;
  const f16x8* pwx2 = (const f16x8*)(ws + OFF_PW2X);
  _Float16* premb = (_Float16*)(ws + OFF_PREMB);

  f16x8 bw[5][10];
#pragma unroll
  for (int n = 0; n < 5; ++n)
#pragma unroll
    for (int kt = 0; kt < 10; ++kt)
      bw[n][kt] = pwx2[(size_t)(kt * 20 + (5 * w + n)) * 64 + l];

  float bb[5];
#pragma unroll
  for (int n = 0; n < 5; ++n) {
    int j = 16 * (5 * w + n) + m;
    bb[n] = (j < 300) ? b1[j] : 0.f;
  }
  // zero the ENTIRE At buffer once (K-pad cols 300..327 must be zero for kt=9)
  {
    unsigned int* a32 = (unsigned int*)(&At[0]);
    for (int idx = tid; idx < 16 * HSTRIDE / 2; idx += 256) a32[idx] = 0u;
  }

  for (int mt = 0; mt < 4; ++mt) {
    const int vbase = blockIdx.x * 64 + mt * 16;
    __syncthreads();
#pragma unroll
    for (int q = 0; q < 5; ++q) {
      int idx = tid + 256 * q;
      if (idx < 1200) {
        int i = idx / 75, cc = idx % 75;
        float4 v = *(const float4*)(emb + (size_t)(vbase + i) * 300 + cc * 4);
        f16x4 fr = {(_Float16)v.x, (_Float16)v.y, (_Float16)v.z, (_Float16)v.w};
        *(f16x4*)(&At[i * HSTRIDE + cc * 4]) = fr;
      }
    }
    __syncthreads();
    f32x4 c[5];
#pragma unroll
    for (int n = 0; n < 5; ++n) c[n] = (f32x4){0.f, 0.f, 0.f, 0.f};
#pragma unroll
    for (int kt = 0; kt < 10; ++kt) {
      f16x8 a = *(const f16x8*)(&At[m * HSTRIDE + kt * 32 + g * 8]);
#pragma unroll
      for (int n = 0; n < 5; ++n) c[n] = mfma16(a, bw[n][kt], c[n]);
    }
#pragma unroll
    for (int n = 0; n < 5; ++n) {
      int j = 16 * (5 * w + n) + m;
      if (j < 300) {
#pragma unroll
        for (int r = 0; r < 4; ++r) {
          int v = vbase + 4 * g + r;
          premb[(size_t)v * 304 + j] = (_Float16)(c[n][r] + bb[n]);
        }
      }
    }
  }
}

// ---------------- phase2: the recurrence ----------------
__global__ __launch_bounds__(512, 1) void rnn_phase2(const int* __restrict__ x,
                                                     unsigned char* __restrict__ ws) {
  __shared__ _Float16 Hb[2][16 * HSTRIDE];
  __shared__ uint4 Pst[2][608];                     // premb stage: [row 0..15][304 halves]
  const int tid = threadIdx.x;
  const int w = tid >> 6, l = tid & 63, g = l >> 4, m = l & 15;
  const int blk = blockIdx.x;
  const int ncnt = (w < 4) ? 3 : 2;                 // waves 0-3: 3 j-tiles, 4-7: 2
  const int jt0 = (w < 4) ? 3 * w : 12 + 2 * (w - 4);
  const f16x8* pwh2 = (const f16x8*)(ws + OFF_PW2H);
  const uint4* prembc = (const uint4*)(ws + OFF_PREMB);  // 38 chunks per vocab row
  unsigned short* hall = (unsigned short*)(ws + OFF_HALL);

  f16x8 bw[3][10];
#pragma unroll
  for (int n = 0; n < 3; ++n)
    if (n < ncnt)
#pragma unroll
      for (int kt = 0; kt < 10; ++kt)
        bw[n][kt] = pwh2[(size_t)(kt * 20 + (jt0 + n)) * 64 + l];

  int jn[3], jv[3];
#pragma unroll
  for (int n = 0; n < 3; ++n) {
    jn[n] = 16 * (jt0 + n) + m;
    jv[n] = (n < ncnt && jn[n] < 300) ? 1 : 0;
  }

  // chunk assignment for staging / hall stores (608 = 16 rows x 38 chunks)
  const int c1 = tid, c2 = 512 + tid;
  const int r1 = c1 / 38, q1 = c1 % 38;
  const int r2 = c2 / 38, q2 = c2 % 38;
  const bool has2 = (tid < 96);

  // zero both H buffers (h0 = 0, plus K-pad columns)
  {
    unsigned int* hb32 = (unsigned int*)(&Hb[0][0]);
    for (int idx = tid; idx < 2 * 16 * HSTRIDE / 2; idx += 512) hb32[idx] = 0u;
  }
  // prime Pst[0] with premb rows for t=0; prime tokens for t=1
  {
    int tka = x[(blk * 16 + r1) * NT + 0];
    Pst[0][c1] = prembc[(size_t)tka * 38 + q1];
    if (has2) {
      int tkb = x[(blk * 16 + r2) * NT + 0];
      Pst[0][c2] = prembc[(size_t)tkb * 38 + q2];
    }
  }
  int tk1 = x[(blk * 16 + r1) * NT + 1];
  int tk2 = has2 ? x[(blk * 16 + r2) * NT + 1] : 0;
  __syncthreads();

  for (int t = 0; t < NT; ++t) {
    const _Float16* Hp = &Hb[t & 1][0];
    _Float16* Hn = &Hb[1 - (t & 1)][0];
    const _Float16* Pcur = (const _Float16*)(&Pst[t & 1][0]);
    uint4* Pnxt = &Pst[1 - (t & 1)][0];

    // 1. epilogue premb values from LDS stage (immediate offsets, issued early)
    float pr[3][4];
#pragma unroll
    for (int n = 0; n < 3; ++n)
#pragma unroll
      for (int r = 0; r < 4; ++r)
        pr[n][r] = jv[n] ? (float)Pcur[(4 * g + r) * 304 + jn[n]] : 0.f;

    // 2. coalesced premb loads for t+1 (consumed at step end -> full-step slack)
    uint4 d1 = prembc[(size_t)tk1 * 38 + q1];
    uint4 d2;
    if (has2) d2 = prembc[(size_t)tk2 * 38 + q2];

    // 3. tokens for t+2 (L1-resident)
    {
      int tt = (t < NT - 2) ? t + 2 : NT - 1;
      tk1 = x[(blk * 16 + r1) * NT + tt];
      if (has2) tk2 = x[(blk * 16 + r2) * NT + tt];
    }

    // 4. hall store of h_t (stable in Hp) -> hall[.][t-1], coalesced
    if (t > 0) {
      uint4 hd1 = *(const uint4*)(Hp + r1 * HSTRIDE + q1 * 8);
      *(uint4*)(&hall[((size_t)(blk * 16 + r1) * NT + (t - 1)) * 304 + q1 * 8]) = hd1;
      if (has2) {
        uint4 hd2 = *(const uint4*)(Hp + r2 * HSTRIDE + q2 * 8);
        *(uint4*)(&hall[((size_t)(blk * 16 + r2) * NT + (t - 1)) * 304 + q2 * 8]) = hd2;
      }
    }

    // 5. MFMA: C = H @ W1h
    f32x4 c[3];
#pragma unroll
    for (int n = 0; n < 3; ++n) c[n] = (f32x4){0.f, 0.f, 0.f, 0.f};
#pragma unroll
    for (int kt = 0; kt < 10; ++kt) {
      f16x8 a = *(const f16x8*)(Hp + m * HSTRIDE + kt * 32 + g * 8);
#pragma unroll
      for (int n = 0; n < 3; ++n)
        if (n < ncnt) c[n] = mfma16(a, bw[n][kt], c[n]);
    }

    // 6. epilogue: h = sigmoid(C + premb) -> Hn (LDS)
#pragma unroll
    for (int n = 0; n < 3; ++n) {
      if (jv[n]) {
#pragma unroll
        for (int r = 0; r < 4; ++r) {
          float val = c[n][r] + pr[n][r];
          float ex = __expf(-val);
          float h = __builtin_amdgcn_rcpf(1.f + ex);
          Hn[(4 * g + r) * HSTRIDE + jn[n]] = (_Float16)h;
        }
      }
    }

    // 7. stage premb for t+1
    Pnxt[c1] = d1;
    if (has2) Pnxt[c2] = d2;

    // 8. barrier (LDS only; global stores stay in flight)
    barrier_lgkm();
  }

  // final h_512 lives in Hb[0] (NT even) -> hall[.][NT-1]
  {
    uint4 hd1 = *(const uint4*)(&Hb[0][0] + r1 * HSTRIDE + q1 * 8);
    *(uint4*)(&hall[((size_t)(blk * 16 + r1) * NT + (NT - 1)) * 304 + q1 * 8]) = hd1;
    if (has2) {
      uint4 hd2 = *(const uint4*)(&Hb[0][0] + r2 * HSTRIDE + q2 * 8);
      *(uint4*)(&hall[((size_t)(blk * 16 + r2) * NT + (NT - 1)) * 304 + q2 * 8]) = hd2;
    }
  }
}

// ---------------- phase3: out = h @ W23 + b23 ----------------
typedef _Float16 half2v __attribute__((ext_vector_type(2)));

__global__ __launch_bounds__(256) void rnn_phase3(const unsigned char* __restrict__ ws,
                                                  float* __restrict__ out) {
  int gw = (blockIdx.x * 256 + threadIdx.x) >> 6;  // one wave per (b,t) row
  int lane = threadIdx.x & 63;
  const unsigned int* hall = (const unsigned int*)(ws + OFF_HALL);
  const float* w23 = (const float*)(ws + OFF_W23);
  const float* b23 = (const float*)(ws + OFF_B23);
  const unsigned int* hr = hall + (size_t)gw * 152u;   // 152 u32 = 304 halves per row
  unsigned int h0 = hr[lane];
  unsigned int h1 = hr[64 + lane];
  unsigned int h2 = (lane < 22) ? hr[128 + lane] : 0u; // pairs 128..149 -> j 256..299
  float s0 = 0.f, s1 = 0.f;
  {
    int p = lane;
    half2v hv = __builtin_bit_cast(half2v, h0);
    float e0 = (float)hv.x, e1 = (float)hv.y;
    s0 += e0 * w23[(2 * p) * 2 + 0] + e1 * w23[(2 * p + 1) * 2 + 0];
    s1 += e0 * w23[(2 * p) * 2 + 1] + e1 * w23[(2 * p + 1) * 2 + 1];
  }
  {
    int p = 64 + lane;
    half2v hv = __builtin_bit_cast(half2v, h1);
    float e0 = (float)hv.x, e1 = (float)hv.y;
    s0 += e0 * w23[(2 * p) * 2 + 0] + e1 * w23[(2 * p + 1) * 2 + 0];
    s1 += e0 * w23[(2 * p) * 2 + 1] + e1 * w23[(2 * p + 1) * 2 + 1];
  }
  if (lane < 22) {
    int p = 128 + lane;
    half2v hv = __builtin_bit_cast(half2v, h2);
    float e0 = (float)hv.x, e1 = (float)hv.y;
    s0 += e0 * w23[(2 * p) * 2 + 0] + e1 * w23[(2 * p + 1) * 2 + 0];
    s1 += e0 * w23[(2 * p) * 2 + 1] + e1 * w23[(2 * p + 1) * 2 + 1];
  }
  for (int mmask = 32; mmask; mmask >>= 1) {
    s0 += __shfl_xor(s0, mmask, 64);
    s1 += __shfl_xor(s1, mmask, 64);
  }
  if (lane == 0) {
    float2 o;
    o.x = s0 + b23[0];
    o.y = s1 + b23[1];
    *(float2*)(out + (size_t)gw * 2) = o;
  }
}

extern "C" void kernel_launch(void* const* d_in, const int* in_sizes, int n_in,
                              void* d_out, int out_size, void* d_ws, size_t ws_size,
                              hipStream_t stream) {
  const int* x = (const int*)d_in[0];
  const float* emb = (const float*)d_in[1];
  const float* W1 = (const float*)d_in[2];
  const float* b1 = (const float*)d_in[3];
  const float* W2 = (const float*)d_in[4];
  const float* b2 = (const float*)d_in[5];
  const float* W3 = (const float*)d_in[6];
  const float* b3 = (const float*)d_in[7];
  unsigned char* ws = (unsigned char*)d_ws;
  float* out = (float*)d_out;

  hipLaunchKernelGGL(rnn_prep, dim3(802), dim3(256), 0, stream, W1, W2, b2, W3, b3, ws);
  hipLaunchKernelGGL(rnn_phase1, dim3(500), dim3(256), 0, stream, emb, b1, ws);
  hipLaunchKernelGGL(rnn_phase2, dim3(8), dim3(512), 0, stream, x, ws);
  hipLaunchKernelGGL(rnn_phase3, dim3(16384), dim3(256), 0, stream, ws, out);
}

// Round 7
// 732.459 us; speedup vs baseline: 3.4066x; 1.0531x over previous
//
#include <hip/hip_runtime.h>
#include <hip/hip_fp16.h>

// Elman RNN via MFMA (R7):
//   phase2: 1024 thr / 16 waves (4/SIMD), 19 j-tiles split {1x13, 2x3};
//   Pst stride 312 halves kills the 4-way g-alias bank conflict;
//   premb read from LDS in epilogue; raw lgkm-only barrier per step.

typedef _Float16 f16x8 __attribute__((ext_vector_type(8)));
typedef _Float16 f16x4 __attribute__((ext_vector_type(4)));
typedef float f32x4 __attribute__((ext_vector_type(4)));

#define NVOCAB 32000
#define NB 128
#define NT 512

// workspace byte offsets (premb strided 304 halves/row = 38 uint4)
#define OFF_PREMB 0ull                 // f16 [32000][304]            = 19,456,000
#define OFF_HALL  19456000ull          // u16 [65536][304]            = 39,845,888
#define OFF_PW2X  59301888ull          // f16 frag table [10][20][64][8] = 204,800
#define OFF_PW2H  59506688ull          // f16 frag table                 = 204,800
#define OFF_W23   59711488ull          // f32 [300][2]                =      2,400
#define OFF_B23   59713888ull          // f32 [2]

#define HSTRIDE 328                    // halves per H-tile row (656B)
#define PSTRIDE 312                    // halves per Pst row (624B = 39 uint4)

__device__ __forceinline__ f32x4 mfma16(f16x8 a, f16x8 b, f32x4 c) {
  return __builtin_amdgcn_mfma_f32_16x16x32_f16(a, b, c, 0, 0, 0);
}

// barrier that waits ONLY LDS ops; global stores stay in flight
__device__ __forceinline__ void barrier_lgkm() {
  asm volatile("s_waitcnt lgkmcnt(0)\n\ts_barrier" ::: "memory");
}

// ---------------- prep: fragment tables + W23/b23 ----------------
// B-frag convention: element e of lane l holds W[k=32*kt+8*(l/16)+e][j=16*jt+(l%16)],
// zero-padded outside 300x300.
__global__ __launch_bounds__(256) void rnn_prep(const float* __restrict__ W1,
                                                const float* __restrict__ W2,
                                                const float* __restrict__ b2,
                                                const float* __restrict__ W3,
                                                const float* __restrict__ b3,
                                                unsigned char* __restrict__ ws) {
  unsigned int tid = blockIdx.x * 256 + threadIdx.x;
  if (tid < 204800u) {
    int part = tid / 102400;          // 0 = W1x (k rows 0..299), 1 = W1h (rows 300..599)
    int f = tid % 102400;
    int e = f & 7, l = (f >> 3) & 63, jt = (f >> 9) % 20, kt = f / 10240;
    int g = l >> 4, m = l & 15;
    int k = 32 * kt + 8 * g + e;
    int j = 16 * jt + m;
    _Float16 val = (_Float16)0.f;
    if (k < 300 && j < 300) val = (_Float16)W1[(size_t)(part * 300 + k) * 300 + j];
    ((_Float16*)(ws + (part ? OFF_PW2H : OFF_PW2X)))[f] = val;
  } else if (tid < 205100u) {
    int j = tid - 204800;
    float s0 = 0.f, s1 = 0.f;
    for (int k = 0; k < 300; ++k) {
      float w = W2[j * 300 + k];
      s0 += w * W3[k * 2 + 0];
      s1 += w * W3[k * 2 + 1];
    }
    float* w23 = (float*)(ws + OFF_W23);
    w23[j * 2 + 0] = s0;
    w23[j * 2 + 1] = s1;
  } else if (tid == 205100u) {
    float s0 = b3[0], s1 = b3[1];
    for (int k = 0; k < 300; ++k) {
      s0 += b2[k] * W3[k * 2 + 0];
      s1 += b2[k] * W3[k * 2 + 1];
    }
    float* b23 = (float*)(ws + OFF_B23);
    b23[0] = s0; b23[1] = s1;
  }
}

// ---------------- phase1: premb = f16(emb @ W1x + b1), stride 304 ----------------
__global__ __launch_bounds__(256, 1) void rnn_phase1(const float* __restrict__ emb,
                                                     const float* __restrict__ b1,
                                                     unsigned char* __restrict__ ws) {
  __shared__ _Float16 At[16 * HSTRIDE];
  const int tid = threadIdx.x;
  const int w = tid >> 6, l = tid & 63, g = l >> 4, m = l & 15;
  const f16x8* pwx2 = (const f16x8*)(ws + OFF_PW2X);
  _Float16* premb = (_Float16*)(ws + OFF_PREMB);

  f16x8 bw[5][10];
#pragma unroll
  for (int n = 0; n < 5; ++n)
#pragma unroll
    for (int kt = 0; kt < 10; ++kt)
      bw[n][kt] = pwx2[(size_t)(kt * 20 + (5 * w + n)) * 64 + l];

  float bb[5];
#pragma unroll
  for (int n = 0; n < 5; ++n) {
    int j = 16 * (5 * w + n) + m;
    bb[n] = (j < 300) ? b1[j] : 0.f;
  }
  // zero the ENTIRE At buffer once (K-pad cols 300..327 must be zero for kt=9)
  {
    unsigned int* a32 = (unsigned int*)(&At[0]);
    for (int idx = tid; idx < 16 * HSTRIDE / 2; idx += 256) a32[idx] = 0u;
  }

  for (int mt = 0; mt < 4; ++mt) {
    const int vbase = blockIdx.x * 64 + mt * 16;
    __syncthreads();
#pragma unroll
    for (int q = 0; q < 5; ++q) {
      int idx = tid + 256 * q;
      if (idx < 1200) {
        int i = idx / 75, cc = idx % 75;
        float4 v = *(const float4*)(emb + (size_t)(vbase + i) * 300 + cc * 4);
        f16x4 fr = {(_Float16)v.x, (_Float16)v.y, (_Float16)v.z, (_Float16)v.w};
        *(f16x4*)(&At[i * HSTRIDE + cc * 4]) = fr;
      }
    }
    __syncthreads();
    f32x4 c[5];
#pragma unroll
    for (int n = 0; n < 5; ++n) c[n] = (f32x4){0.f, 0.f, 0.f, 0.f};
#pragma unroll
    for (int kt = 0; kt < 10; ++kt) {
      f16x8 a = *(const f16x8*)(&At[m * HSTRIDE + kt * 32 + g * 8]);
#pragma unroll
      for (int n = 0; n < 5; ++n) c[n] = mfma16(a, bw[n][kt], c[n]);
    }
#pragma unroll
    for (int n = 0; n < 5; ++n) {
      int j = 16 * (5 * w + n) + m;
      if (j < 300) {
#pragma unroll
        for (int r = 0; r < 4; ++r) {
          int v = vbase + 4 * g + r;
          premb[(size_t)v * 304 + j] = (_Float16)(c[n][r] + bb[n]);
        }
      }
    }
  }
}

// ---------------- phase2: the recurrence (16 waves) ----------------
__global__ __launch_bounds__(1024, 4) void rnn_phase2(const int* __restrict__ x,
                                                      unsigned char* __restrict__ ws) {
  __shared__ _Float16 Hb[2][16 * HSTRIDE];
  __shared__ uint4 Pst[2][16 * 39];                 // premb stage, stride 39 uint4/row
  const int tid = threadIdx.x;
  const int w = tid >> 6, l = tid & 63, g = l >> 4, m = l & 15;
  const int blk = blockIdx.x;
  // 19 j-tiles over 16 waves: waves 0-12 one tile, 13-15 two tiles
  const int ncnt = (w < 13) ? 1 : 2;
  const int jt0 = (w < 13) ? w : 13 + 2 * (w - 13);
  const f16x8* pwh2 = (const f16x8*)(ws + OFF_PW2H);
  const uint4* prembc = (const uint4*)(ws + OFF_PREMB);  // 38 chunks per vocab row
  unsigned short* hall = (unsigned short*)(ws + OFF_HALL);

  f16x8 bw[2][10];                                  // <=80 VGPRs
#pragma unroll
  for (int n = 0; n < 2; ++n)
    if (n < ncnt)
#pragma unroll
      for (int kt = 0; kt < 10; ++kt)
        bw[n][kt] = pwh2[(size_t)(kt * 20 + (jt0 + n)) * 64 + l];

  int jn[2], jv[2];
#pragma unroll
  for (int n = 0; n < 2; ++n) {
    jn[n] = 16 * (jt0 + n) + m;
    jv[n] = (n < ncnt && jn[n] < 300) ? 1 : 0;
  }

  // chunk assignment: 608 chunks (16 rows x 38), threads 0..607 one each
  const bool hasC = (tid < 608);
  const int r1 = tid / 38, q1 = tid % 38;

  // zero both H buffers (h0 = 0, plus K-pad columns)
  {
    unsigned int* hb32 = (unsigned int*)(&Hb[0][0]);
    for (int idx = tid; idx < 2 * 16 * HSTRIDE / 2; idx += 1024) hb32[idx] = 0u;
  }
  int tk1 = 0;
  if (hasC) {
    int tka = x[(blk * 16 + r1) * NT + 0];
    Pst[0][r1 * 39 + q1] = prembc[(size_t)tka * 38 + q1];
    tk1 = x[(blk * 16 + r1) * NT + 1];
  }
  __syncthreads();

  for (int t = 0; t < NT; ++t) {
    const _Float16* Hp = &Hb[t & 1][0];
    _Float16* Hn = &Hb[1 - (t & 1)][0];
    const _Float16* Pcur = (const _Float16*)(&Pst[t & 1][0]);
    uint4* Pnxt = &Pst[1 - (t & 1)][0];

    // 1. coalesced premb loads for t+1 (consumed at step end -> full-step slack)
    uint4 d1;
    if (hasC) d1 = prembc[(size_t)tk1 * 38 + q1];

    // 2. tokens for t+2 (L1-resident)
    if (hasC) {
      int tt = (t < NT - 2) ? t + 2 : NT - 1;
      tk1 = x[(blk * 16 + r1) * NT + tt];
    }

    // 3. hall store of h_t (stable in Hp) -> hall[.][t-1], coalesced
    if (t > 0 && hasC) {
      uint4 hd1 = *(const uint4*)(Hp + r1 * HSTRIDE + q1 * 8);
      *(uint4*)(&hall[((size_t)(blk * 16 + r1) * NT + (t - 1)) * 304 + q1 * 8]) = hd1;
    }

    // 4. MFMA: C = H @ W1h
    f32x4 c[2];
#pragma unroll
    for (int n = 0; n < 2; ++n) c[n] = (f32x4){0.f, 0.f, 0.f, 0.f};
#pragma unroll
    for (int kt = 0; kt < 10; ++kt) {
      f16x8 a = *(const f16x8*)(Hp + m * HSTRIDE + kt * 32 + g * 8);
#pragma unroll
      for (int n = 0; n < 2; ++n)
        if (n < ncnt) c[n] = mfma16(a, bw[n][kt], c[n]);
    }

    // 5. epilogue: h = sigmoid(C + premb) -> Hn (LDS); premb from Pst (stride 312)
#pragma unroll
    for (int n = 0; n < 2; ++n) {
      if (jv[n]) {
#pragma unroll
        for (int r = 0; r < 4; ++r) {
          float val = c[n][r] + (float)Pcur[(4 * g + r) * PSTRIDE + jn[n]];
          float ex = __expf(-val);
          float h = __builtin_amdgcn_rcpf(1.f + ex);
          Hn[(4 * g + r) * HSTRIDE + jn[n]] = (_Float16)h;
        }
      }
    }

    // 6. stage premb for t+1
    if (hasC) Pnxt[r1 * 39 + q1] = d1;

    // 7. barrier (LDS only; global stores stay in flight)
    barrier_lgkm();
  }

  // final h_512 lives in Hb[0] (NT even) -> hall[.][NT-1]
  if (hasC) {
    uint4 hd1 = *(const uint4*)(&Hb[0][0] + r1 * HSTRIDE + q1 * 8);
    *(uint4*)(&hall[((size_t)(blk * 16 + r1) * NT + (NT - 1)) * 304 + q1 * 8]) = hd1;
  }
}

// ---------------- phase3: out = h @ W23 + b23 ----------------
typedef _Float16 half2v __attribute__((ext_vector_type(2)));

__global__ __launch_bounds__(256) void rnn_phase3(const unsigned char* __restrict__ ws,
                                                  float* __restrict__ out) {
  int gw = (blockIdx.x * 256 + threadIdx.x) >> 6;  // one wave per (b,t) row
  int lane = threadIdx.x & 63;
  const unsigned int* hall = (const unsigned int*)(ws + OFF_HALL);
  const float* w23 = (const float*)(ws + OFF_W23);
  const float* b23 = (const float*)(ws + OFF_B23);
  const unsigned int* hr = hall + (size_t)gw * 152u;   // 152 u32 = 304 halves per row
  unsigned int h0 = hr[lane];
  unsigned int h1 = hr[64 + lane];
  unsigned int h2 = (lane < 22) ? hr[128 + lane] : 0u; // pairs 128..149 -> j 256..299
  float s0 = 0.f, s1 = 0.f;
  {
    int p = lane;
    half2v hv = __builtin_bit_cast(half2v, h0);
    float e0 = (float)hv.x, e1 = (float)hv.y;
    s0 += e0 * w23[(2 * p) * 2 + 0] + e1 * w23[(2 * p + 1) * 2 + 0];
    s1 += e0 * w23[(2 * p) * 2 + 1] + e1 * w23[(2 * p + 1) * 2 + 1];
  }
  {
    int p = 64 + lane;
    half2v hv = __builtin_bit_cast(half2v, h1);
    float e0 = (float)hv.x, e1 = (float)hv.y;
    s0 += e0 * w23[(2 * p) * 2 + 0] + e1 * w23[(2 * p + 1) * 2 + 0];
    s1 += e0 * w23[(2 * p) * 2 + 1] + e1 * w23[(2 * p + 1) * 2 + 1];
  }
  if (lane < 22) {
    int p = 128 + lane;
    half2v hv = __builtin_bit_cast(half2v, h2);
    float e0 = (float)hv.x, e1 = (float)hv.y;
    s0 += e0 * w23[(2 * p) * 2 + 0] + e1 * w23[(2 * p + 1) * 2 + 0];
    s1 += e0 * w23[(2 * p) * 2 + 1] + e1 * w23[(2 * p + 1) * 2 + 1];
  }
  for (int mmask = 32; mmask; mmask >>= 1) {
    s0 += __shfl_xor(s0, mmask, 64);
    s1 += __shfl_xor(s1, mmask, 64);
  }
  if (lane == 0) {
    float2 o;
    o.x = s0 + b23[0];
    o.y = s1 + b23[1];
    *(float2*)(out + (size_t)gw * 2) = o;
  }
}

extern "C" void kernel_launch(void* const* d_in, const int* in_sizes, int n_in,
                              void* d_out, int out_size, void* d_ws, size_t ws_size,
                              hipStream_t stream) {
  const int* x = (const int*)d_in[0];
  const float* emb = (const float*)d_in[1];
  const float* W1 = (const float*)d_in[2];
  const float* b1 = (const float*)d_in[3];
  const float* W2 = (const float*)d_in[4];
  const float* b2 = (const float*)d_in[5];
  const float* W3 = (const float*)d_in[6];
  const float* b3 = (const float*)d_in[7];
  unsigned char* ws = (unsigned char*)d_ws;
  float* out = (float*)d_out;

  hipLaunchKernelGGL(rnn_prep, dim3(802), dim3(256), 0, stream, W1, W2, b2, W3, b3, ws);
  hipLaunchKernelGGL(rnn_phase1, dim3(500), dim3(256), 0, stream, emb, b1, ws);
  hipLaunchKernelGGL(rnn_phase2, dim3(8), dim3(1024), 0, stream, x, ws);
  hipLaunchKernelGGL(rnn_phase3, dim3(16384), dim3(256), 0, stream, ws, out);
}

// Round 8
// 728.917 us; speedup vs baseline: 3.4231x; 1.0049x over previous
//
#include <hip/hip_runtime.h>
#include <hip/hip_fp16.h>

// Elman RNN via MFMA (R8):
//   conflict-free LDS layout: HSTRIDE 332 halves (166 dwords == 6 mod 32).
//   A-fragments read as 2 x ds_read_b64 (rows are 8B-aligned, not 16B) ->
//   banks uniform 4-deep (= b64 floor), no conflict cycles.
//   Everything else as R7: 16 waves, Pst stride 312, lgkm-only barrier.

typedef _Float16 f16x8 __attribute__((ext_vector_type(8)));
typedef _Float16 f16x4 __attribute__((ext_vector_type(4)));
typedef float f32x4 __attribute__((ext_vector_type(4)));

#define NVOCAB 32000
#define NB 128
#define NT 512

// workspace byte offsets (premb strided 304 halves/row = 38 uint4)
#define OFF_PREMB 0ull                 // f16 [32000][304]            = 19,456,000
#define OFF_HALL  19456000ull          // u16 [65536][304]            = 39,845,888
#define OFF_PW2X  59301888ull          // f16 frag table [10][20][64][8] = 204,800
#define OFF_PW2H  59506688ull          // f16 frag table                 = 204,800
#define OFF_W23   59711488ull          // f32 [300][2]                =      2,400
#define OFF_B23   59713888ull          // f32 [2]

#define HSTRIDE 332                    // halves per H row: 166 dwords == 6 mod 32 (conflict-free)
#define PSTRIDE 312                    // halves per Pst row (624B = 39 uint4)

__device__ __forceinline__ f32x4 mfma16(f16x8 a, f16x8 b, f32x4 c) {
  return __builtin_amdgcn_mfma_f32_16x16x32_f16(a, b, c, 0, 0, 0);
}

// load an A-fragment as two 8B LDS reads (rows are only 8B-aligned by design)
__device__ __forceinline__ f16x8 load_afrag(const _Float16* p) {
  f16x4 lo = *(const f16x4*)(p);
  f16x4 hi = *(const f16x4*)(p + 4);
  return __builtin_shufflevector(lo, hi, 0, 1, 2, 3, 4, 5, 6, 7);
}

// barrier that waits ONLY LDS ops; global stores stay in flight
__device__ __forceinline__ void barrier_lgkm() {
  asm volatile("s_waitcnt lgkmcnt(0)\n\ts_barrier" ::: "memory");
}

// ---------------- prep: fragment tables + W23/b23 ----------------
// B-frag convention: element e of lane l holds W[k=32*kt+8*(l/16)+e][j=16*jt+(l%16)],
// zero-padded outside 300x300.
__global__ __launch_bounds__(256) void rnn_prep(const float* __restrict__ W1,
                                                const float* __restrict__ W2,
                                                const float* __restrict__ b2,
                                                const float* __restrict__ W3,
                                                const float* __restrict__ b3,
                                                unsigned char* __restrict__ ws) {
  unsigned int tid = blockIdx.x * 256 + threadIdx.x;
  if (tid < 204800u) {
    int part = tid / 102400;          // 0 = W1x (k rows 0..299), 1 = W1h (rows 300..599)
    int f = tid % 102400;
    int e = f & 7, l = (f >> 3) & 63, jt = (f >> 9) % 20, kt = f / 10240;
    int g = l >> 4, m = l & 15;
    int k = 32 * kt + 8 * g + e;
    int j = 16 * jt + m;
    _Float16 val = (_Float16)0.f;
    if (k < 300 && j < 300) val = (_Float16)W1[(size_t)(part * 300 + k) * 300 + j];
    ((_Float16*)(ws + (part ? OFF_PW2H : OFF_PW2X)))[f] = val;
  } else if (tid < 205100u) {
    int j = tid - 204800;
    float s0 = 0.f, s1 = 0.f;
    for (int k = 0; k < 300; ++k) {
      float w = W2[j * 300 + k];
      s0 += w * W3[k * 2 + 0];
      s1 += w * W3[k * 2 + 1];
    }
    float* w23 = (float*)(ws + OFF_W23);
    w23[j * 2 + 0] = s0;
    w23[j * 2 + 1] = s1;
  } else if (tid == 205100u) {
    float s0 = b3[0], s1 = b3[1];
    for (int k = 0; k < 300; ++k) {
      s0 += b2[k] * W3[k * 2 + 0];
      s1 += b2[k] * W3[k * 2 + 1];
    }
    float* b23 = (float*)(ws + OFF_B23);
    b23[0] = s0; b23[1] = s1;
  }
}

// ---------------- phase1: premb = f16(emb @ W1x + b1), stride 304 ----------------
__global__ __launch_bounds__(256, 1) void rnn_phase1(const float* __restrict__ emb,
                                                     const float* __restrict__ b1,
                                                     unsigned char* __restrict__ ws) {
  __shared__ _Float16 At[16 * HSTRIDE];
  const int tid = threadIdx.x;
  const int w = tid >> 6, l = tid & 63, g = l >> 4, m = l & 15;
  const f16x8* pwx2 = (const f16x8*)(ws + OFF_PW2X);
  _Float16* premb = (_Float16*)(ws + OFF_PREMB);

  f16x8 bw[5][10];
#pragma unroll
  for (int n = 0; n < 5; ++n)
#pragma unroll
    for (int kt = 0; kt < 10; ++kt)
      bw[n][kt] = pwx2[(size_t)(kt * 20 + (5 * w + n)) * 64 + l];

  float bb[5];
#pragma unroll
  for (int n = 0; n < 5; ++n) {
    int j = 16 * (5 * w + n) + m;
    bb[n] = (j < 300) ? b1[j] : 0.f;
  }
  // zero the ENTIRE At buffer once (K-pad cols 300..331 must be zero for kt=9)
  {
    unsigned int* a32 = (unsigned int*)(&At[0]);
    for (int idx = tid; idx < 16 * HSTRIDE / 2; idx += 256) a32[idx] = 0u;
  }

  for (int mt = 0; mt < 4; ++mt) {
    const int vbase = blockIdx.x * 64 + mt * 16;
    __syncthreads();
#pragma unroll
    for (int q = 0; q < 5; ++q) {
      int idx = tid + 256 * q;
      if (idx < 1200) {
        int i = idx / 75, cc = idx % 75;
        float4 v = *(const float4*)(emb + (size_t)(vbase + i) * 300 + cc * 4);
        f16x4 fr = {(_Float16)v.x, (_Float16)v.y, (_Float16)v.z, (_Float16)v.w};
        *(f16x4*)(&At[i * HSTRIDE + cc * 4]) = fr;
      }
    }
    __syncthreads();
    f32x4 c[5];
#pragma unroll
    for (int n = 0; n < 5; ++n) c[n] = (f32x4){0.f, 0.f, 0.f, 0.f};
#pragma unroll
    for (int kt = 0; kt < 10; ++kt) {
      f16x8 a = load_afrag(&At[m * HSTRIDE + kt * 32 + g * 8]);
#pragma unroll
      for (int n = 0; n < 5; ++n) c[n] = mfma16(a, bw[n][kt], c[n]);
    }
#pragma unroll
    for (int n = 0; n < 5; ++n) {
      int j = 16 * (5 * w + n) + m;
      if (j < 300) {
#pragma unroll
        for (int r = 0; r < 4; ++r) {
          int v = vbase + 4 * g + r;
          premb[(size_t)v * 304 + j] = (_Float16)(c[n][r] + bb[n]);
        }
      }
    }
  }
}

// ---------------- phase2: the recurrence (16 waves) ----------------
__global__ __launch_bounds__(1024, 4) void rnn_phase2(const int* __restrict__ x,
                                                      unsigned char* __restrict__ ws) {
  __shared__ _Float16 Hb[2][16 * HSTRIDE];
  __shared__ uint4 Pst[2][16 * 39];                 // premb stage, stride 39 uint4/row
  const int tid = threadIdx.x;
  const int w = tid >> 6, l = tid & 63, g = l >> 4, m = l & 15;
  const int blk = blockIdx.x;
  // 19 j-tiles over 16 waves: waves 0-12 one tile, 13-15 two tiles
  const int ncnt = (w < 13) ? 1 : 2;
  const int jt0 = (w < 13) ? w : 13 + 2 * (w - 13);
  const f16x8* pwh2 = (const f16x8*)(ws + OFF_PW2H);
  const uint4* prembc = (const uint4*)(ws + OFF_PREMB);  // 38 chunks per vocab row
  unsigned short* hall = (unsigned short*)(ws + OFF_HALL);

  f16x8 bw[2][10];
#pragma unroll
  for (int n = 0; n < 2; ++n)
    if (n < ncnt)
#pragma unroll
      for (int kt = 0; kt < 10; ++kt)
        bw[n][kt] = pwh2[(size_t)(kt * 20 + (jt0 + n)) * 64 + l];

  int jn[2], jv[2];
#pragma unroll
  for (int n = 0; n < 2; ++n) {
    jn[n] = 16 * (jt0 + n) + m;
    jv[n] = (n < ncnt && jn[n] < 300) ? 1 : 0;
  }

  // chunk assignment: 608 chunks (16 rows x 38), threads 0..607 one each
  const bool hasC = (tid < 608);
  const int r1 = tid / 38, q1 = tid % 38;

  // zero both H buffers (h0 = 0, plus K-pad columns)
  {
    unsigned int* hb32 = (unsigned int*)(&Hb[0][0]);
    for (int idx = tid; idx < 2 * 16 * HSTRIDE / 2; idx += 1024) hb32[idx] = 0u;
  }
  int tk1 = 0;
  if (hasC) {
    int tka = x[(blk * 16 + r1) * NT + 0];
    Pst[0][r1 * 39 + q1] = prembc[(size_t)tka * 38 + q1];
    tk1 = x[(blk * 16 + r1) * NT + 1];
  }
  __syncthreads();

  for (int t = 0; t < NT; ++t) {
    const _Float16* Hp = &Hb[t & 1][0];
    _Float16* Hn = &Hb[1 - (t & 1)][0];
    const _Float16* Pcur = (const _Float16*)(&Pst[t & 1][0]);
    uint4* Pnxt = &Pst[1 - (t & 1)][0];

    // 1. coalesced premb loads for t+1 (consumed at step end -> full-step slack)
    uint4 d1;
    if (hasC) d1 = prembc[(size_t)tk1 * 38 + q1];

    // 2. tokens for t+2 (L1-resident)
    if (hasC) {
      int tt = (t < NT - 2) ? t + 2 : NT - 1;
      tk1 = x[(blk * 16 + r1) * NT + tt];
    }

    // 3. hall store of h_t (stable in Hp) -> hall[.][t-1], coalesced.
    //    LDS rows are 8B-aligned -> read as 2 x b64.
    if (t > 0 && hasC) {
      uint2 hlo = *(const uint2*)(Hp + r1 * HSTRIDE + q1 * 8);
      uint2 hhi = *(const uint2*)(Hp + r1 * HSTRIDE + q1 * 8 + 4);
      uint4 hd1 = {hlo.x, hlo.y, hhi.x, hhi.y};
      *(uint4*)(&hall[((size_t)(blk * 16 + r1) * NT + (t - 1)) * 304 + q1 * 8]) = hd1;
    }

    // 4. MFMA: C = H @ W1h
    f32x4 c[2];
#pragma unroll
    for (int n = 0; n < 2; ++n) c[n] = (f32x4){0.f, 0.f, 0.f, 0.f};
#pragma unroll
    for (int kt = 0; kt < 10; ++kt) {
      f16x8 a = load_afrag(Hp + m * HSTRIDE + kt * 32 + g * 8);
#pragma unroll
      for (int n = 0; n < 2; ++n)
        if (n < ncnt) c[n] = mfma16(a, bw[n][kt], c[n]);
    }

    // 5. epilogue: h = sigmoid(C + premb) -> Hn (LDS); premb from Pst (stride 312)
#pragma unroll
    for (int n = 0; n < 2; ++n) {
      if (jv[n]) {
#pragma unroll
        for (int r = 0; r < 4; ++r) {
          float val = c[n][r] + (float)Pcur[(4 * g + r) * PSTRIDE + jn[n]];
          float ex = __expf(-val);
          float h = __builtin_amdgcn_rcpf(1.f + ex);
          Hn[(4 * g + r) * HSTRIDE + jn[n]] = (_Float16)h;
        }
      }
    }

    // 6. stage premb for t+1
    if (hasC) Pnxt[r1 * 39 + q1] = d1;

    // 7. barrier (LDS only; global stores stay in flight)
    barrier_lgkm();
  }

  // final h_512 lives in Hb[0] (NT even) -> hall[.][NT-1]
  if (hasC) {
    uint2 hlo = *(const uint2*)(&Hb[0][0] + r1 * HSTRIDE + q1 * 8);
    uint2 hhi = *(const uint2*)(&Hb[0][0] + r1 * HSTRIDE + q1 * 8 + 4);
    uint4 hd1 = {hlo.x, hlo.y, hhi.x, hhi.y};
    *(uint4*)(&hall[((size_t)(blk * 16 + r1) * NT + (NT - 1)) * 304 + q1 * 8]) = hd1;
  }
}

// ---------------- phase3: out = h @ W23 + b23 ----------------
typedef _Float16 half2v __attribute__((ext_vector_type(2)));

__global__ __launch_bounds__(256) void rnn_phase3(const unsigned char* __restrict__ ws,
                                                  float* __restrict__ out) {
  int gw = (blockIdx.x * 256 + threadIdx.x) >> 6;  // one wave per (b,t) row
  int lane = threadIdx.x & 63;
  const unsigned int* hall = (const unsigned int*)(ws + OFF_HALL);
  const float* w23 = (const float*)(ws + OFF_W23);
  const float* b23 = (const float*)(ws + OFF_B23);
  const unsigned int* hr = hall + (size_t)gw * 152u;   // 152 u32 = 304 halves per row
  unsigned int h0 = hr[lane];
  unsigned int h1 = hr[64 + lane];
  unsigned int h2 = (lane < 22) ? hr[128 + lane] : 0u; // pairs 128..149 -> j 256..299
  float s0 = 0.f, s1 = 0.f;
  {
    int p = lane;
    half2v hv = __builtin_bit_cast(half2v, h0);
    float e0 = (float)hv.x, e1 = (float)hv.y;
    s0 += e0 * w23[(2 * p) * 2 + 0] + e1 * w23[(2 * p + 1) * 2 + 0];
    s1 += e0 * w23[(2 * p) * 2 + 1] + e1 * w23[(2 * p + 1) * 2 + 1];
  }
  {
    int p = 64 + lane;
    half2v hv = __builtin_bit_cast(half2v, h1);
    float e0 = (float)hv.x, e1 = (float)hv.y;
    s0 += e0 * w23[(2 * p) * 2 + 0] + e1 * w23[(2 * p + 1) * 2 + 0];
    s1 += e0 * w23[(2 * p) * 2 + 1] + e1 * w23[(2 * p + 1) * 2 + 1];
  }
  if (lane < 22) {
    int p = 128 + lane;
    half2v hv = __builtin_bit_cast(half2v, h2);
    float e0 = (float)hv.x, e1 = (float)hv.y;
    s0 += e0 * w23[(2 * p) * 2 + 0] + e1 * w23[(2 * p + 1) * 2 + 0];
    s1 += e0 * w23[(2 * p) * 2 + 1] + e1 * w23[(2 * p + 1) * 2 + 1];
  }
  for (int mmask = 32; mmask; mmask >>= 1) {
    s0 += __shfl_xor(s0, mmask, 64);
    s1 += __shfl_xor(s1, mmask, 64);
  }
  if (lane == 0) {
    float2 o;
    o.x = s0 + b23[0];
    o.y = s1 + b23[1];
    *(float2*)(out + (size_t)gw * 2) = o;
  }
}

extern "C" void kernel_launch(void* const* d_in, const int* in_sizes, int n_in,
                              void* d_out, int out_size, void* d_ws, size_t ws_size,
                              hipStream_t stream) {
  const int* x = (const int*)d_in[0];
  const float* emb = (const float*)d_in[1];
  const float* W1 = (const float*)d_in[2];
  const float* b1 = (const float*)d_in[3];
  const float* W2 = (const float*)d_in[4];
  const float* b2 = (const float*)d_in[5];
  const float* W3 = (const float*)d_in[6];
  const float* b3 = (const float*)d_in[7];
  unsigned char* ws = (unsigned char*)d_ws;
  float* out = (float*)d_out;

  hipLaunchKernelGGL(rnn_prep, dim3(802), dim3(256), 0, stream, W1, W2, b2, W3, b3, ws);
  hipLaunchKernelGGL(rnn_phase1, dim3(500), dim3(256), 0, stream, emb, b1, ws);
  hipLaunchKernelGGL(rnn_phase2, dim3(8), dim3(1024), 0, stream, x, ws);
  hipLaunchKernelGGL(rnn_phase3, dim3(16384), dim3(256), 0, stream, ws, out);
}